// Round 8
// baseline (134.253 us; speedup 1.0000x reference)
//
#include <hip/hip_runtime.h>

#define NG 128      // graphs
#define NPG 64      // nodes per graph
#define IN 16
#define DM 128      // d_model
#define NOUT 64
#define EPG 4096    // edges per graph (64x64)
#define NCH 128     // gemm chunks: 64 k-chunks(80) x 2 f-halves(64)
#define BN_EPS 1e-5f

// ---------------------------------------------------------------------------
// Coherence (r5/r6-proven): cross-PHASE stores inside k_tail are agent-scope
// relaxed atomics (sc1 write-through -> IC, no dirty L2); reads after each
// barrier are PLAIN float4 loads made safe by an acquire-only fence
// (L1/L2 invalidate, no writeback). K1->K2 coherence via kernel boundary.
// ---------------------------------------------------------------------------
__device__ __forceinline__ void stg(float* p, float v) {
    __hip_atomic_store(p, v, __ATOMIC_RELAXED, __HIP_MEMORY_SCOPE_AGENT);
}

// Fence-free grid barrier (r5-proven). ctrl u32 layout (memset 0 per launch):
// epoch e in 1..3: sub[8] @ e*160+sg*16, root @ e*160+128; flags[256]
// stride16 @ 1024. Spread-line RMW arrival, root broadcasts 256 private
// lines, t0-only poll + acquire-inv. Profiler replays without the memset
// see flags >= e and fall through (no hang).
__device__ __forceinline__ void gbar(unsigned* bu, unsigned e, int bid, int t,
                                     bool wait) {
    __syncthreads();   // drains vmcnt -> sc1 stores complete at IC
    if (t == 0) {
        unsigned* sub   = bu + e * 160 + (bid & 7) * 16;
        unsigned* root  = bu + e * 160 + 128;
        unsigned* flags = bu + 1024;
        if (atomicAdd(sub, 1u) == 31u)
            if (atomicAdd(root, 1u) == 7u)
                for (int i = 0; i < 256; i++)
                    __hip_atomic_store(&flags[i * 16], e,
                                       __ATOMIC_RELAXED, __HIP_MEMORY_SCOPE_AGENT);
        if (wait) {
            while (__hip_atomic_load(&flags[bid * 16],
                                     __ATOMIC_RELAXED, __HIP_MEMORY_SCOPE_AGENT) < e)
                __builtin_amdgcn_s_sleep(1);
            __builtin_amdgcn_fence(__ATOMIC_ACQUIRE, "agent");   // inv L1+L2
        }
    }
    __syncthreads();
}

// ---------------------------------------------------------------------------
// K_A "front": 256 blocks x 512 threads (r7 verbatim, passed).
//   blocks 0..127  = conv1 per graph -> pooled -> ppart (Wm0[0:128] product)
//   blocks 128..255 = big-GEMM x/ew chunks (80k x 64f) -> part
// ---------------------------------------------------------------------------
__global__ __launch_bounds__(512) void k_front(
    const float* __restrict__ x, const float* __restrict__ ew,
    const float* __restrict__ W1, const float* __restrict__ b1,
    const float* __restrict__ W2, const float* __restrict__ b2,
    const float* __restrict__ Wm0,
    float* __restrict__ part, float* __restrict__ ppart,
    float* __restrict__ stats)
{
    __shared__ __align__(16) float u[16128];   // 63KB union
    const int bid = blockIdx.x, t = threadIdx.x;

    if (bid < 128) {
        float* ew_s     = u;             // [i][j] 4096 (raw)
        float* x_s      = u + 4096;      // x^T [k][i] 1024
        float* W1_s     = u + 5120;      // [k][f] 2048
        float* P_s      = u + 7168;      // [i][f] 8192 (dinv_i * P)
        float* b1_s     = u + 15360;     // 128
        float* dinv_s   = u + 15488;     // 64
        float* t_s      = u + 15552;     // 64
        float* zp       = u + 4096;      // overlay: 16*132
        float* z_full   = u + 15616;     // 128
        float* pooled_s = u + 15744;     // 128
        float* pp4      = u + 4096;      // overlay 2: 512
        const int g = bid;
        if (bid == 0) {
            for (int i = t; i < 768; i += 512) stats[i] = 0.f;
        }
        {
            const float4* ew4 = (const float4*)(ew + g * EPG);
            float4* ews4 = (float4*)ew_s;
            ews4[t]       = ew4[t];
            ews4[t + 512] = ew4[t + 512];
            if (t < 256) {
                const int xi = t & 63, k4 = (t >> 6) * 4;
                float4 xv = *(const float4*)(x + g * NPG * IN + xi * IN + k4);
                x_s[(k4 + 0) * 64 + xi] = xv.x;
                x_s[(k4 + 1) * 64 + xi] = xv.y;
                x_s[(k4 + 2) * 64 + xi] = xv.z;
                x_s[(k4 + 3) * 64 + xi] = xv.w;
            }
            ((float4*)W1_s)[t] = ((const float4*)W1)[t];
            if (t < 128) b1_s[t] = b1[t];
        }
        __syncthreads();

        if (t < NPG) {
            float s = 0.f;
            #pragma unroll 8
            for (int i = 0; i < NPG; i++) s += ew_s[i * NPG + t];
            dinv_s[t] = (s > 0.f) ? rsqrtf(s) : 0.f;
        }
        __syncthreads();

        {   // t_s[i] = dinv_i * (sum_j ew[i,j] dinv_j) / 64  (8 waves x 8 rows)
            const int j = t & 63, q = t >> 6;
            const float dj = dinv_s[j];
            for (int i = q * 8; i < q * 8 + 8; i++) {
                float vv = ew_s[i * NPG + j] * dj;
                #pragma unroll
                for (int off = 32; off > 0; off >>= 1) vv += __shfl_down(vv, off, 64);
                if (j == 0) t_s[i] = dinv_s[i] * vv * (1.f / 64.f);
            }
        }

        {   // P' = dinv_i * (x @ W1), 16x32 grid, 4x4 acc
            const int it = t & 15, ft = t >> 4;
            const int i0 = it * 4, f0 = ft * 4;
            float accp[4][4];
            #pragma unroll
            for (int a = 0; a < 4; a++)
                #pragma unroll
                for (int c = 0; c < 4; c++) accp[a][c] = 0.f;
            #pragma unroll
            for (int k = 0; k < IN; k++) {
                const float4 a4 = *(const float4*)(x_s + k * 64 + i0);
                const float4 b4 = *(const float4*)(W1_s + k * DM + f0);
                const float av[4] = {a4.x, a4.y, a4.z, a4.w};
                const float bv[4] = {b4.x, b4.y, b4.z, b4.w};
                #pragma unroll
                for (int a = 0; a < 4; a++)
                    #pragma unroll
                    for (int c = 0; c < 4; c++) accp[a][c] += av[a] * bv[c];
            }
            #pragma unroll
            for (int a = 0; a < 4; a++) {
                const float di = dinv_s[i0 + a];
                *(float4*)(P_s + (i0 + a) * DM + f0) =
                    make_float4(di * accp[a][0], di * accp[a][1],
                                di * accp[a][2], di * accp[a][3]);
            }
        }
        __syncthreads();

        {   // aggregation + z-partials, 16x32 grid, 4x4 acc
            const int jt = t & 15, ft = t >> 4;
            const int j0 = jt * 4, f0 = ft * 4;
            float acc[4][4];
            #pragma unroll
            for (int a = 0; a < 4; a++)
                #pragma unroll
                for (int c = 0; c < 4; c++) acc[a][c] = 0.f;
            #pragma unroll 4
            for (int k = 0; k < 64; k++) {
                const float4 a4 = *(const float4*)(ew_s + k * 64 + j0);
                const float4 b4 = *(const float4*)(P_s + k * DM + f0);
                const float av[4] = {a4.x, a4.y, a4.z, a4.w};
                const float bv[4] = {b4.x, b4.y, b4.z, b4.w};
                #pragma unroll
                for (int a = 0; a < 4; a++)
                    #pragma unroll
                    for (int c = 0; c < 4; c++) acc[a][c] += av[a] * bv[c];
            }
            float zpart[4];
            #pragma unroll
            for (int c = 0; c < 4; c++) zpart[c] = 0.f;
            #pragma unroll
            for (int a = 0; a < 4; a++) {
                const float dj = dinv_s[j0 + a], tj = t_s[j0 + a];
                #pragma unroll
                for (int c = 0; c < 4; c++) {
                    float h = fmaxf(dj * acc[a][c] + b1_s[f0 + c], 0.f);
                    zpart[c] += tj * h;
                }
            }
            *(float4*)(zp + jt * 132 + f0) =
                make_float4(zpart[0], zpart[1], zpart[2], zpart[3]);
        }
        __syncthreads();

        if (t < 128) {
            float s = 0.f;
            #pragma unroll
            for (int jt = 0; jt < 16; jt++) s += zp[jt * 132 + t];
            z_full[t] = s;
        }
        __syncthreads();

        {   // pooled = relu(z @ W2 + b2)
            const int c = t & 127, kh = t >> 7;
            float acc = 0.f;
            #pragma unroll 8
            for (int k = kh * 32; k < kh * 32 + 32; k++)
                acc += z_full[k] * W2[k * DM + c];
            pp4[kh * 128 + c] = acc;
        }
        __syncthreads();
        if (t < 128)
            pooled_s[t] = fmaxf(pp4[t] + pp4[128 + t] + pp4[256 + t] + pp4[384 + t]
                                + b2[t], 0.f);
        __syncthreads();

        {   // ppart = pooled @ Wm0[0:128,:]
            const int f = t & 127, kh = t >> 7;
            float acc = 0.f;
            #pragma unroll 8
            for (int k = kh * 32; k < kh * 32 + 32; k++)
                acc += pooled_s[k] * Wm0[k * DM + f];
            pp4[kh * 128 + f] = acc;
        }
        __syncthreads();
        if (t < 128)
            ppart[g * DM + t] = pp4[t] + pp4[128 + t] + pp4[256 + t] + pp4[384 + t];
    } else {
        // ---------------- gemm x/ew chunk path (K=80) ----------------
        const int c = bid - 128;
        const int kc = c >> 1, fh = c & 1;
        const int K0 = kc * 80;
        float* a_s = u;                  // [k][g] 80*132 = 10560
        float* b_s = u + 10560;          // [k][fl] 80*64 = 5120

        float4 ra[4], ra2, rb[3];
        #pragma unroll
        for (int it = 0; it < 4; it++) {
            int idx = it * 512 + t;
            int gg = idx >> 4, k4 = (idx & 15) << 2;
            int K = K0 + k4;
            const float* src = (K < 1024) ? (x + gg * 1024 + K)
                                          : (ew + gg * 4096 + (K - 1024));
            ra[it] = *(const float4*)src;
        }
        {
            int gg = t >> 2, k4 = 64 + ((t & 3) << 2);
            int K = K0 + k4;
            const float* src = (K < 1024) ? (x + gg * 1024 + K)
                                          : (ew + gg * 4096 + (K - 1024));
            ra2 = *(const float4*)src;
        }
        #pragma unroll
        for (int it = 0; it < 3; it++) {
            int idx = it * 512 + t;
            if (idx < 1280) {
                int k = idx >> 4, fl4 = (idx & 15) << 2;
                rb[it] = *(const float4*)(Wm0 + (size_t)(128 + K0 + k) * 128
                                          + fh * 64 + fl4);
            }
        }
        #pragma unroll
        for (int it = 0; it < 4; it++) {
            int idx = it * 512 + t;
            int gg = idx >> 4, k4 = (idx & 15) << 2;
            a_s[(k4 + 0) * 132 + gg] = fmaxf(ra[it].x, 0.f);
            a_s[(k4 + 1) * 132 + gg] = fmaxf(ra[it].y, 0.f);
            a_s[(k4 + 2) * 132 + gg] = fmaxf(ra[it].z, 0.f);
            a_s[(k4 + 3) * 132 + gg] = fmaxf(ra[it].w, 0.f);
        }
        {
            int gg = t >> 2, k4 = 64 + ((t & 3) << 2);
            a_s[(k4 + 0) * 132 + gg] = fmaxf(ra2.x, 0.f);
            a_s[(k4 + 1) * 132 + gg] = fmaxf(ra2.y, 0.f);
            a_s[(k4 + 2) * 132 + gg] = fmaxf(ra2.z, 0.f);
            a_s[(k4 + 3) * 132 + gg] = fmaxf(ra2.w, 0.f);
        }
        #pragma unroll
        for (int it = 0; it < 3; it++) {
            int idx = it * 512 + t;
            if (idx < 1280) {
                int k = idx >> 4, fl4 = (idx & 15) << 2;
                *(float4*)(b_s + k * 64 + fl4) = rb[it];
            }
        }
        __syncthreads();

        const int gthr = t & 31, fthr = t >> 5;   // 32 x 16
        const int g0 = gthr * 4, f0 = fthr * 4;
        float acc[4][4];
        #pragma unroll
        for (int i = 0; i < 4; i++)
            #pragma unroll
            for (int jx = 0; jx < 4; jx++) acc[i][jx] = 0.f;

        #pragma unroll 4
        for (int k = 0; k < 80; k++) {
            const float4 a4 = *(const float4*)(a_s + k * 132 + g0);
            const float4 b4 = *(const float4*)(b_s + k * 64 + f0);
            const float av[4] = {a4.x, a4.y, a4.z, a4.w};
            const float bv[4] = {b4.x, b4.y, b4.z, b4.w};
            #pragma unroll
            for (int i = 0; i < 4; i++)
                #pragma unroll
                for (int jx = 0; jx < 4; jx++) acc[i][jx] += av[i] * bv[jx];
        }

        float* pp = part + (size_t)c * 8192;    // [g][fl] 128x64
        #pragma unroll
        for (int i = 0; i < 4; i++)
            *(float4*)(pp + (g0 + i) * 64 + f0) =
                make_float4(acc[i][0], acc[i][1], acc[i][2], acc[i][3]);
    }
}

// ---------------------------------------------------------------------------
// MLP phase (r0 k_mlp body; plain float4 reads are safe post-acquire).
// 256 blocks = 128 f-cols x 2 graph-halves.
// ---------------------------------------------------------------------------
__device__ void mlp_phase(float* u, int bid, int t,
    const float* __restrict__ vin, const float* __restrict__ statsin,
    const float* __restrict__ gbn, const float* __restrict__ bbn,
    const float* __restrict__ W, const float* __restrict__ bias,
    float* __restrict__ vout, float* __restrict__ statsout)
{
    float* scale_s = u;          // 128
    float* shift_s = u + 128;    // 128
    float* wcol    = u + 256;    // 128
    float* pc      = u + 384;    // 256
    float* h_s     = u + 640;    // 64*129 = 8256
    const int f = bid & 127, gh = bid >> 7;
    if (t < 128) {
        float s1 = statsin[t * 2], s2 = statsin[t * 2 + 1];
        float m = s1 * (1.f / 128.f);
        float var = s2 * (1.f / 128.f) - m * m;
        float sc = gbn[t] * rsqrtf(var + BN_EPS);
        scale_s[t] = sc;
        shift_s[t] = bbn[t] - m * sc;
        wcol[t] = W[t * 128 + f];
    }
    __syncthreads();
    const int g0r = gh * 64;
    const float4* vin4 = (const float4*)(vin + g0r * 128);
    #pragma unroll
    for (int it = 0; it < 8; ++it) {
        int idx = it * 256 + t;            // 2048 float4 = 64 rows x 128
        int gl = idx >> 5, k4 = (idx & 31) * 4;
        float4 vv = vin4[idx];
        float* hp = h_s + gl * 129 + k4;
        hp[0] = vv.x * scale_s[k4 + 0] + shift_s[k4 + 0];
        hp[1] = vv.y * scale_s[k4 + 1] + shift_s[k4 + 1];
        hp[2] = vv.z * scale_s[k4 + 2] + shift_s[k4 + 2];
        hp[3] = vv.w * scale_s[k4 + 3] + shift_s[k4 + 3];
    }
    __syncthreads();
    {
        const int gl = t & 63, kh = t >> 6;
        float acc = 0.f;
        #pragma unroll 8
        for (int k = kh * 32; k < kh * 32 + 32; ++k)
            acc += h_s[gl * 129 + k] * wcol[k];
        pc[gl * 4 + kh] = acc;
    }
    __syncthreads();
    if (t < 64) {   // wave 0
        float v = fmaxf(pc[t * 4] + pc[t * 4 + 1] + pc[t * 4 + 2] + pc[t * 4 + 3]
                        + bias[f], 0.f);
        stg(&vout[(size_t)(g0r + t) * 128 + f], v);
        float s1 = v, s2 = v * v;
        #pragma unroll
        for (int off = 32; off > 0; off >>= 1) {
            s1 += __shfl_down(s1, off, 64);
            s2 += __shfl_down(s2, off, 64);
        }
        if (t == 0) {
            atomicAdd(&statsout[f * 2], s1);
            atomicAdd(&statsout[f * 2 + 1], s2);
        }
    }
}

// ---------------------------------------------------------------------------
// K_tail: R+bn0 |bar| M1 |bar| M2 |bar(exit>=128)| O.  256 blocks x 256 thr.
// Replaces 3 kernel-launch boundaries with 3 in-kernel barriers — the
// decisive boundary-vs-barrier cost experiment.
// ---------------------------------------------------------------------------
__global__ __launch_bounds__(256) void k_tail(
    const float* __restrict__ part, const float* __restrict__ ppart,
    const float* __restrict__ bm0,
    const float* __restrict__ gbn0, const float* __restrict__ bbn0,
    const float* __restrict__ Wm1, const float* __restrict__ bm1,
    const float* __restrict__ gbn1, const float* __restrict__ bbn1,
    const float* __restrict__ Wm2, const float* __restrict__ bm2,
    const float* __restrict__ gbn2, const float* __restrict__ bbn2,
    const float* __restrict__ Wo, const float* __restrict__ bo,
    float* __restrict__ ws, float* __restrict__ out)
{
    __shared__ __align__(16) float u[9216];    // 36KB union
    unsigned* bu = (unsigned*)ws;              // ctrl 5120 u32 (memset 0)
    float* stats = ws + 1292288;               // after v2 (see launch layout)
    float* v0    = ws + 1243136;               // part(5120+1048576)+ppart(16384)
    float* v1    = v0 + 16384;
    float* v2    = v1 + 16384;
    const int bid = blockIdx.x, t = threadIdx.x;

    // ============ phase R: reduce part + bn0 (32 gt x 8 fgrp) ============
    {
        float* r1  = u;          // 1024
        float* sv  = u + 1024;   // 64
        float* sv2 = u + 1088;   // 64
        const int fgrp = bid & 7, gt = bid >> 3;
        const int f4 = t & 3, gl = (t >> 2) & 3, ch = t >> 4;
        const int g = gt * 4 + gl;
        const int fbase = fgrp * 16 + f4 * 4;
        const int fh = fbase >> 6, fl = fbase & 63;
        const float4* p = (const float4*)part
                        + ((size_t)(2 * (ch * 4) + fh) * 8192 + g * 64 + fl) / 4;
        float4 v = make_float4(0.f, 0.f, 0.f, 0.f);
        #pragma unroll
        for (int cc = 0; cc < 4; cc++) {
            float4 x4 = p[(size_t)cc * 4096];   // +2*8192 floats per k-chunk
            v.x += x4.x; v.y += x4.y; v.z += x4.z; v.w += x4.w;
        }
        float* r = r1 + ch * 64 + gl * 16 + f4 * 4;
        r[0] = v.x; r[1] = v.y; r[2] = v.z; r[3] = v.w;
        __syncthreads();

        if (t < 64) {
            const int fsub = t & 15, gl2 = t >> 4;
            const int f = fgrp * 16 + fsub, gg = gt * 4 + gl2;
            float s = bm0[f] + ppart[gg * DM + f];
            #pragma unroll
            for (int c2 = 0; c2 < 16; c2++) s += r1[c2 * 64 + gl2 * 16 + fsub];
            s = fmaxf(s, 0.f);
            stg(&v0[gg * DM + f], s);
            sv[t] = s; sv2[t] = s * s;
        }
        __syncthreads();
        if (t < 16) {
            float s1 = sv[t] + sv[t + 16] + sv[t + 32] + sv[t + 48];
            float s2 = sv2[t] + sv2[t + 16] + sv2[t + 32] + sv2[t + 48];
            atomicAdd(&stats[(fgrp * 16 + t) * 2], s1);
            atomicAdd(&stats[(fgrp * 16 + t) * 2 + 1], s2);
        }
    }
    gbar(bu, 1u, bid, t, true);

    // ======================= phases M1, M2 =======================
    mlp_phase(u, bid, t, v0, stats,       gbn0, bbn0, Wm1, bm1, v1, stats + 256);
    gbar(bu, 2u, bid, t, true);
    mlp_phase(u, bid, t, v1, stats + 256, gbn1, bbn1, Wm2, bm2, v2, stats + 512);
    gbar(bu, 3u, bid, t, bid < 128);   // blocks >=128 arrive and exit
    if (bid >= 128) return;

    // ============ phase O: BN2 + output (128 blocks x 1 graph) ============
    {
        float* Wo_s = u;            // 8192 (32KB)
        float* vrow = u + 8192;     // 128
        float* sc   = u + 8320;     // 128
        float* sh   = u + 8448;     // 128
        float* pc   = u + 8576;     // 256
        const float* st2 = stats + 512;
        const int g = bid;
        if (t < 128) {
            float s1 = st2[t * 2], s2 = st2[t * 2 + 1];
            float m = s1 * (1.f / 128.f);
            float var = s2 * (1.f / 128.f) - m * m;
            float scv = gbn2[t] * rsqrtf(var + BN_EPS);
            sc[t] = scv;
            sh[t] = bbn2[t] - m * scv;
        }
        {   // stage Wo 128x64 (2048 float4)
            const float4* wo4 = (const float4*)Wo;
            float4* wos4 = (float4*)Wo_s;
            #pragma unroll
            for (int it = 0; it < 8; it++) wos4[it * 256 + t] = wo4[it * 256 + t];
        }
        __syncthreads();
        if (t < 128) vrow[t] = v2[(size_t)g * 128 + t] * sc[t] + sh[t];
        __syncthreads();
        {   // 64 o-cols x 4 k-quarters
            const int o = t & 63, kh = t >> 6;
            float acc = 0.f;
            #pragma unroll 8
            for (int k = kh * 32; k < kh * 32 + 32; k++)
                acc += vrow[k] * Wo_s[k * 64 + o];
            pc[kh * 64 + o] = acc;
        }
        __syncthreads();
        if (t < 64)
            out[g * NOUT + t] = pc[t] + pc[64 + t] + pc[128 + t] + pc[192 + t] + bo[t];
    }
}

extern "C" void kernel_launch(void* const* d_in, const int* in_sizes, int n_in,
                              void* d_out, int out_size, void* d_ws, size_t ws_size,
                              hipStream_t stream)
{
    const float* x   = (const float*)d_in[0];
    const float* ew  = (const float*)d_in[2];
    const float* W1  = (const float*)d_in[4];
    const float* b1  = (const float*)d_in[5];
    const float* W2  = (const float*)d_in[6];
    const float* b2  = (const float*)d_in[7];
    const float* Wm0 = (const float*)d_in[8];
    const float* bm0 = (const float*)d_in[9];
    const float* g0  = (const float*)d_in[10];
    const float* be0 = (const float*)d_in[11];
    const float* Wm1 = (const float*)d_in[12];
    const float* bm1 = (const float*)d_in[13];
    const float* g1  = (const float*)d_in[14];
    const float* be1 = (const float*)d_in[15];
    const float* Wm2 = (const float*)d_in[16];
    const float* bm2 = (const float*)d_in[17];
    const float* g2  = (const float*)d_in[18];
    const float* be2 = (const float*)d_in[19];
    const float* Wo  = (const float*)d_in[20];
    const float* bo  = (const float*)d_in[21];

    float* ws     = (float*)d_ws;
    // float-offset layout (keep k_tail's hard-coded offsets in sync):
    float* part   = ws + 5120;                // barrier ctrl occupies [0,5120)
    float* ppartb = part + NCH * 8192;        // 1048576 -> ppart @ 1053696
    float* v0     = ppartb + 16384;           // @ 1243136 + 5120 - 5120 ... v0 @ ws+1243136? no:
    // ppartb = ws + 5120 + 1048576 = ws + 1053696; v0 = ws + 1070080
    // (k_tail recomputes: v0 = ws + 1243136 must match -> fix here instead)
    v0 = ws + 1243136;
    float* v1     = v0 + 16384;
    float* v2     = v1 + 16384;
    float* stats  = ws + 1292288;             // 768 (stats0|stats1|stats2)

    // zero barrier ctrl (20 KB); stats zeroed inside k_front (bid 0)
    hipMemsetAsync(d_ws, 0, 20480, stream);
    k_front<<<256, 512, 0, stream>>>(x, ew, W1, b1, W2, b2, Wm0,
                                     part, ppartb, stats);
    k_tail<<<256, 256, 0, stream>>>(part, ppartb, bm0,
                                    g0, be0, Wm1, bm1,
                                    g1, be1, Wm2, bm2,
                                    g2, be2, Wo, bo,
                                    ws, (float*)d_out);
}